// Round 10
// baseline (1495.328 us; speedup 1.0000x reference)
//
#include <hip/hip_runtime.h>

#define CDIV(a,b) (((a)+(b)-1)/(b))

typedef unsigned short u16;
typedef __attribute__((ext_vector_type(8))) short s16x8;
typedef __attribute__((ext_vector_type(4))) float fx4;

#define NBATCH 8
#define MTOK 197
#define DIM 384
#define EDIM 768
#define NST 16
#define NROWS (NBATCH*MTOK)      // 1576
#define PADROWS 1664             // 13*128
#define ENC (EDIM*NST)           // 12288
#define NBIG (2*ENC+EDIM)        // 25344
#define NCH 16                   // scan chunks
#define CLEN 13                  // ceil(197/16)
#define SCANT (NBATCH*EDIM*NST)  // 98304 scan lanes

__device__ __forceinline__ u16 f2b(float f) {
  union { float f; unsigned u; } v; v.f = f;
  unsigned r = v.u + 0x7fffu + ((v.u >> 16) & 1u);
  return (u16)(r >> 16);
}
__device__ __forceinline__ float b2f(u16 u) {
  union { unsigned u; float f; } v; v.u = ((unsigned)u) << 16;
  return v.f;
}
__device__ __forceinline__ float silu_f(float x) { return x / (1.f + __expf(-x)); }
__device__ __forceinline__ float softplus_f(float x) {
  return (x > 15.f) ? x : log1pf(__expf(x));
}

#define GLD16(g, l) __builtin_amdgcn_global_load_lds( \
    (const __attribute__((address_space(1))) void*)(g), \
    (__attribute__((address_space(3))) void*)(l), 16, 0, 0)

// bijective XCD-contiguous block remap [m204]
__device__ __forceinline__ int xcd_swz(int orig, int nwg) {
  int q = nwg >> 3, r = nwg & 7;
  int xcd = orig & 7, pos = orig >> 3;
  return (xcd < r ? xcd*(q+1) : r*(q+1) + (xcd-r)*q) + pos;
}

// ---------------------------------------------------------------- im2col
__global__ void im2col_k(float* __restrict__ dst, const float* __restrict__ x) {
  int i = blockIdx.x*blockDim.x + threadIdx.x;
  if (i >= 1600*768) return;
  int col = i % 768, r = i / 768;
  float v = 0.f;
  if (r < 1568) {
    int b = r / 196, p = r % 196;
    int py = p / 14, px = p % 14;
    int c = col >> 8, rem = col & 255;
    int ph = rem >> 4, pw_ = rem & 15;
    v = x[((b*3 + c)*224 + py*16 + ph)*224 + px*16 + pw_];
  }
  dst[i] = v;
}

// --------------------------------------------- fp32 patch-embed GEMM (precision-critical)
__global__ __launch_bounds__(256) void patch_gemm_k(
    const float* __restrict__ A, const float* __restrict__ W,
    const float* __restrict__ pb, const float* __restrict__ pos, float* __restrict__ t) {
  __shared__ float As[64][17], Ws[64][17];
  int bx = blockIdx.x % 25, by = blockIdx.x / 25;
  int tid = threadIdx.x;
  int tx = tid & 15, ty = tid >> 4;
  float acc[4][4] = {};
  for (int kk = 0; kk < 768; kk += 16) {
    #pragma unroll
    for (int l = 0; l < 4; ++l) {
      int e = tid + l*256;
      int r = e >> 4, c = e & 15;
      As[r][c] = A[(size_t)(bx*64 + r)*768 + kk + c];
      Ws[r][c] = W[(size_t)(by*64 + r)*768 + kk + c];
    }
    __syncthreads();
    #pragma unroll
    for (int k = 0; k < 16; ++k) {
      float av[4], bv[4];
      #pragma unroll
      for (int i2 = 0; i2 < 4; ++i2) av[i2] = As[ty*4+i2][k];
      #pragma unroll
      for (int j = 0; j < 4; ++j) bv[j] = Ws[tx*4+j][k];
      #pragma unroll
      for (int i2 = 0; i2 < 4; ++i2)
        #pragma unroll
        for (int j = 0; j < 4; ++j)
          acc[i2][j] += av[i2]*bv[j];
    }
    __syncthreads();
  }
  #pragma unroll
  for (int i2 = 0; i2 < 4; ++i2) {
    int R = bx*64 + ty*4 + i2;
    if (R >= 1568) continue;
    int b = R / 196, p = R % 196;
    float* trow = t + ((size_t)b*MTOK + 1 + p)*DIM;
    const float* prow = pos + (size_t)(1+p)*DIM;
    #pragma unroll
    for (int j = 0; j < 4; ++j) {
      int Dd = by*64 + tx*4 + j;
      trow[Dd] = acc[i2][j] + pb[Dd] + prow[Dd];
    }
  }
}

__global__ void cls_add_k(float* __restrict__ t, const float* __restrict__ cls,
                          const float* __restrict__ pos) {
  int i = blockIdx.x*blockDim.x + threadIdx.x;
  if (i >= NBATCH*DIM) return;
  int b = i / DIM, d = i % DIM;
  t[(size_t)b*MTOK*DIM + d] = cls[d] + pos[d];
}

// ---------------------------------------------------------------- final LayerNorm (f32 out)
__global__ __launch_bounds__(64) void ln_k(const float* __restrict__ x,
    const float* __restrict__ g, const float* __restrict__ bb, float* __restrict__ y) {
  int row = blockIdx.x, lane = threadIdx.x;
  const float* xr = x + (size_t)row*DIM;
  float v[6]; float s = 0.f;
  #pragma unroll
  for (int i = 0; i < 6; ++i) { v[i] = xr[lane + i*64]; s += v[i]; }
  #pragma unroll
  for (int o = 32; o >= 1; o >>= 1) s += __shfl_xor(s, o);
  float mean = s * (1.f/DIM);
  float q = 0.f;
  #pragma unroll
  for (int i = 0; i < 6; ++i) { float d = v[i]-mean; q += d*d; }
  #pragma unroll
  for (int o = 32; o >= 1; o >>= 1) q += __shfl_xor(q, o);
  float rstd = rsqrtf(q*(1.f/DIM) + 1e-5f);
  float* yr = y + (size_t)row*DIM;
  #pragma unroll
  for (int i = 0; i < 6; ++i) {
    int c = lane + i*64;
    yr[c] = (v[i]-mean)*rstd*g[c] + bb[c];
  }
}

// ---------------------------- per-layer LayerNorm -> bf16 padded A (rows>=NROWS zeroed)
__global__ __launch_bounds__(64) void ln_bf_k(const float* __restrict__ x,
    const float* __restrict__ g, const float* __restrict__ bb, u16* __restrict__ y) {
  int row = blockIdx.x, lane = threadIdx.x;
  u16* yr = y + (size_t)row*DIM;
  if (row >= NROWS) {
    #pragma unroll
    for (int i = 0; i < 6; ++i) yr[lane + i*64] = 0;
    return;
  }
  const float* xr = x + (size_t)row*DIM;
  float v[6]; float s = 0.f;
  #pragma unroll
  for (int i = 0; i < 6; ++i) { v[i] = xr[lane + i*64]; s += v[i]; }
  #pragma unroll
  for (int o = 32; o >= 1; o >>= 1) s += __shfl_xor(s, o);
  float mean = s * (1.f/DIM);
  float q = 0.f;
  #pragma unroll
  for (int i = 0; i < 6; ++i) { float d = v[i]-mean; q += d*d; }
  #pragma unroll
  for (int o = 32; o >= 1; o >>= 1) q += __shfl_xor(q, o);
  float rstd = rsqrtf(q*(1.f/DIM) + 1e-5f);
  #pragma unroll
  for (int i = 0; i < 6; ++i) {
    int c = lane + i*64;
    yr[c] = f2b((v[i]-mean)*rstd*g[c] + bb[c]);
  }
}

// --------------- fused prep: up to-3-segment weight fp32->bf16 + bias concat (f32)
__global__ void prep_k(u16* __restrict__ wdst,
                       const float* __restrict__ w1, int n1,
                       const float* __restrict__ w2, int n2,
                       const float* __restrict__ w3, int n3,
                       float* __restrict__ bdst,
                       const float* __restrict__ b1, int m1,
                       const float* __restrict__ b2, int m2,
                       const float* __restrict__ b3a, const float* __restrict__ b3b, int m3) {
  int ntw = n1 + n2 + n3;
  int i4 = (blockIdx.x*blockDim.x + threadIdx.x)*4;
  if (i4 < ntw) {
    const float* src; int off;
    if (i4 < n1)           { src = w1; off = i4; }
    else if (i4 < n1+n2)   { src = w2; off = i4-n1; }
    else                   { src = w3; off = i4-n1-n2; }
    float4 v = *(const float4*)(src + off);
    *(ushort4*)(wdst + i4) = make_ushort4(f2b(v.x), f2b(v.y), f2b(v.z), f2b(v.w));
  } else {
    int j = i4 - ntw;
    int mt = m1 + m2 + m3;
    #pragma unroll
    for (int k2 = 0; k2 < 4; ++k2) {
      int j2 = j + k2;
      if (j2 < mt) {
        float v;
        if (j2 < m1)          v = b1[j2];
        else if (j2 < m1+m2)  v = b2[j2-m1];
        else { int t2 = j2-m1-m2; v = b3a[t2] + b3b[t2]; }
        bdst[j2] = v;
      }
    }
  }
}

// ---------------------------------------------------------------- bf16 MFMA GEMM (m97 structure + XCD swizzle)
// A: [rows_padded][K] bf16 row-major, W: [N][K] bf16 row-major (i.e. B^T), out = A*W^T + bias
// MODE 0: f32 out; MODE 1: bf16 out; MODE 2: f32 out += (residual accumulate)
template<int MODE>
__global__ __launch_bounds__(256, 5) void gemm_k(
    const u16* __restrict__ A, const u16* __restrict__ W,
    const float* __restrict__ bias, void* __restrict__ outp,
    int Mvalid, int N, int K, int nRT) {
  __shared__ u16 As[128*64];
  __shared__ u16 Bs[128*64];
  int bid = xcd_swz(blockIdx.x, gridDim.x);
  int rt = bid % nRT, ct = bid / nRT;   // col-major grid: consecutive logical blocks share W panel
  int tid = threadIdx.x;
  int w = tid >> 6, lane = tid & 63;
  int wm = w >> 1, wn = w & 1;
  fx4 acc[4][4];
  #pragma unroll
  for (int i = 0; i < 4; ++i)
    #pragma unroll
    for (int j = 0; j < 4; ++j) acc[i][j] = (fx4)0.f;

  int lrow = lane >> 3;
  int lcol = (lane & 7) * 8;
  size_t abase = (size_t)(rt*128) * K + lcol;
  size_t wbase = (size_t)(ct*128) * K + lcol;

  for (int kk = 0; kk < K; kk += 64) {
    #pragma unroll
    for (int c = 0; c < 4; ++c) {
      int chunk = c*4 + w;
      int row = chunk*8 + lrow;
      GLD16(A + abase + (size_t)row*K + kk, As + chunk*512);
      GLD16(W + wbase + (size_t)row*K + kk, Bs + chunk*512);
    }
    __syncthreads();
    #pragma unroll
    for (int ks = 0; ks < 2; ++ks) {
      s16x8 afr[4], bfr[4];
      #pragma unroll
      for (int f = 0; f < 4; ++f) {
        int ar = wm*64 + f*16 + (lane & 15);
        afr[f] = *(const s16x8*)(As + ar*64 + ks*32 + (lane>>4)*8);
        int br = wn*64 + f*16 + (lane & 15);
        bfr[f] = *(const s16x8*)(Bs + br*64 + ks*32 + (lane>>4)*8);
      }
      #pragma unroll
      for (int i = 0; i < 4; ++i)
        #pragma unroll
        for (int j = 0; j < 4; ++j)
          acc[i][j] = __builtin_amdgcn_mfma_f32_16x16x32_bf16(afr[i], bfr[j], acc[i][j], 0, 0, 0);
    }
    __syncthreads();
  }
  // epilogue: C/D layout col=lane&15, row=4*(lane>>4)+reg  [verified m89/m91]
  #pragma unroll
  for (int i = 0; i < 4; ++i) {
    int rbase = rt*128 + wm*64 + i*16 + (lane>>4)*4;
    #pragma unroll
    for (int j = 0; j < 4; ++j) {
      int Cc = ct*128 + wn*64 + j*16 + (lane & 15);
      float bv = bias[Cc];
      #pragma unroll
      for (int r = 0; r < 4; ++r) {
        int R = rbase + r;
        if (R < Mvalid) {
          float v = acc[i][j][r] + bv;
          if (MODE == 0)      ((float*)outp)[(size_t)R*N + Cc] = v;
          else if (MODE == 1) ((u16*)outp)[(size_t)R*N + Cc] = f2b(v);
          else { float* o = (float*)outp + (size_t)R*N + Cc; *o += v; }
        }
      }
    }
  }
}

// -------- fused fwd+bwd depthwise conv (token dim) + silu -> f32 X and bf16 padded A
// also zeroes the pad rows of the 768-wide gate output buffer (gabf)
__global__ void dwconv2_k(const float* __restrict__ xpz,
                          const float* __restrict__ kwf, const float* __restrict__ kbf,
                          const float* __restrict__ kwb, const float* __restrict__ kbb,
                          float* __restrict__ outf, float* __restrict__ outb,
                          u16* __restrict__ af16, u16* __restrict__ ab16,
                          u16* __restrict__ gabf) {
  int i = blockIdx.x*blockDim.x + threadIdx.x;
  if (i >= PADROWS*EDIM) return;
  int e = i % EDIM, r = i / EDIM;
  if (r >= NROWS) { af16[i] = 0; ab16[i] = 0; gabf[i] = 0; return; }
  int t = r % MTOK;
  const float* base = xpz + (size_t)r*(2*EDIM) + e;  // xp at col offset 0, ld=1536
  float xm = (t > 0)        ? base[-(2*EDIM)] : 0.f;
  float x0 = base[0];
  float xp = (t < MTOK-1)   ? base[ (2*EDIM)] : 0.f;
  float vf = silu_f(kbf[e] + xm*kwf[e*3+0] + x0*kwf[e*3+1] + xp*kwf[e*3+2]);
  float vb = silu_f(kbb[e] + xm*kwb[e*3+0] + x0*kwb[e*3+1] + xp*kwb[e*3+2]);
  outf[i] = vf; outb[i] = vb;
  af16[i] = f2b(vf); ab16[i] = f2b(vb);
}

// ---------------------------------------------------------------- chunked selective scan (vectorized)
// 4 n-states per lane: B/C load as ushort4 (8B), h/P/H0 as float4. 16 e per wave group of 4 lanes.
// BC row layout: [0,12288)=B, [12288,24576)=C, [24576,25344)=delta_pre.
__global__ __launch_bounds__(256) void scan_part_k(const u16* __restrict__ BC,
    const float* __restrict__ X, const float* __restrict__ afp,
    float* __restrict__ hend, float* __restrict__ pend, int rev) {
  int w = threadIdx.x >> 6, lane = threadIdx.x & 63;
  int b = blockIdx.y, c = blockIdx.z;
  int e = blockIdx.x*64 + w*16 + (lane >> 2);
  int n0 = (lane & 3) * 4;
  float4 ac = *(const float4*)(afp + e*NST + n0);
  size_t rb = (size_t)b*MTOK;
  int tau0 = c*CLEN;
  int tauE = min(MTOK-1, tau0 + CLEN - 1);
  float h0=0.f,h1=0.f,h2=0.f,h3=0.f, P0=1.f,P1=1.f,P2=1.f,P3=1.f;
  int t0 = rev ? (MTOK-1-tau0) : tau0;
  const u16* q0 = BC + (rb + t0)*NBIG;
  ushort4 Bv = *(const ushort4*)(q0 + e*NST + n0);
  u16 dpu = q0[2*ENC + e];
  float Xv = X[(rb + t0)*EDIM + e];
  for (int tau = tau0; tau <= tauE; ++tau) {
    ushort4 nB = make_ushort4(0,0,0,0); u16 ndp = 0; float nX = 0.f;
    if (tau + 1 <= tauE) {
      int tn = rev ? (MTOK-2-tau) : (tau+1);
      const u16* qn = BC + (rb + tn)*NBIG;
      nB = *(const ushort4*)(qn + e*NST + n0);
      ndp = qn[2*ENC + e];
      nX = X[(rb + tn)*EDIM + e];
    }
    float delta = softplus_f(b2f(dpu));
    float dx = delta * Xv;
    float a0 = delta*ac.x, a1 = delta*ac.y, a2 = delta*ac.z, a3 = delta*ac.w;
    h0 = a0*h0 + b2f(Bv.x)*dx;  P0 *= a0;
    h1 = a1*h1 + b2f(Bv.y)*dx;  P1 *= a1;
    h2 = a2*h2 + b2f(Bv.z)*dx;  P2 *= a2;
    h3 = a3*h3 + b2f(Bv.w)*dx;  P3 *= a3;
    Bv = nB; dpu = ndp; Xv = nX;
  }
  size_t ci = (size_t)c*SCANT + ((size_t)b*EDIM + e)*NST + n0;
  *(float4*)(hend + ci) = make_float4(h0,h1,h2,h3);
  *(float4*)(pend + ci) = make_float4(P0,P1,P2,P3);
}

// Phase 2: sequential carry combine across chunks (tiny)
__global__ void scan_carry_k(const float* __restrict__ hend, const float* __restrict__ pend,
                             float* __restrict__ H0) {
  int i = blockIdx.x*blockDim.x + threadIdx.x;
  if (i >= SCANT) return;
  float H = 0.f;
  #pragma unroll
  for (int c = 0; c < NCH; ++c) {
    size_t ci = (size_t)c*SCANT + i;
    H0[ci] = H;
    H = pend[ci]*H + hend[ci];
  }
}

// Phase 3: re-run chunk recurrence from exact carry-in, emit y = sum_n h*C.
// gate=0: Y[t,e] = ps (forward). gate=1: final=(Y[t,e]+ps); gdst[t,e]=bf16(final*silu(z)).
__global__ __launch_bounds__(256) void scan_emit_k(const u16* __restrict__ BC,
    const float* __restrict__ X, const float* __restrict__ afp,
    const float* __restrict__ H0, float* __restrict__ Y,
    const float* __restrict__ xpz, u16* __restrict__ gdst, int rev, int gate) {
  int w = threadIdx.x >> 6, lane = threadIdx.x & 63;
  int b = blockIdx.y, c = blockIdx.z;
  int e = blockIdx.x*64 + w*16 + (lane >> 2);
  int n0 = (lane & 3) * 4;
  float4 ac = *(const float4*)(afp + e*NST + n0);
  size_t rb = (size_t)b*MTOK;
  int tau0 = c*CLEN;
  int tauE = min(MTOK-1, tau0 + CLEN - 1);
  float4 hh = *(const float4*)(H0 + (size_t)c*SCANT + ((size_t)b*EDIM + e)*NST + n0);
  float h0 = hh.x, h1 = hh.y, h2 = hh.z, h3 = hh.w;
  int t0 = rev ? (MTOK-1-tau0) : tau0;
  const u16* q0 = BC + (rb + t0)*NBIG;
  ushort4 Bv = *(const ushort4*)(q0 + e*NST + n0);
  ushort4 Cv = *(const ushort4*)(q0 + ENC + e*NST + n0);
  u16 dpu = q0[2*ENC + e];
  float Xv = X[(rb + t0)*EDIM + e];
  for (int tau = tau0; tau <= tauE; ++tau) {
    int t = rev ? (MTOK-1-tau) : tau;
    ushort4 nB = make_ushort4(0,0,0,0), nC = make_ushort4(0,0,0,0);
    u16 ndp = 0; float nX = 0.f;
    if (tau + 1 <= tauE) {
      int tn = rev ? (MTOK-2-tau) : (tau+1);
      const u16* qn = BC + (rb + tn)*NBIG;
      nB = *(const ushort4*)(qn + e*NST + n0);
      nC = *(const ushort4*)(qn + ENC + e*NST + n0);
      ndp = qn[2*ENC + e];
      nX = X[(rb + tn)*EDIM + e];
    }
    float delta = softplus_f(b2f(dpu));
    float dx = delta * Xv;
    h0 = (delta*ac.x)*h0 + b2f(Bv.x)*dx;
    h1 = (delta*ac.y)*h1 + b2f(Bv.y)*dx;
    h2 = (delta*ac.z)*h2 + b2f(Bv.z)*dx;
    h3 = (delta*ac.w)*h3 + b2f(Bv.w)*dx;
    float ps = h0*b2f(Cv.x) + h1*b2f(Cv.y) + h2*b2f(Cv.z) + h3*b2f(Cv.w);
    ps += __shfl_xor(ps, 1); ps += __shfl_xor(ps, 2);
    if ((lane & 3) == 0) {
      size_t idx = (rb + t)*EDIM + e;
      if (gate) {
        float yv = Y[idx] + ps;
        float z = xpz[(rb + t)*(size_t)(2*EDIM) + EDIM + e];
        gdst[idx] = f2b(yv * silu_f(z));
      } else {
        Y[idx] = ps;
      }
    }
    Bv = nB; Cv = nC; dpu = ndp; Xv = nX;
  }
}

// ================================================================ host
extern "C" void kernel_launch(void* const* d_in, const int* in_sizes, int n_in,
                              void* d_out, int out_size, void* d_ws, size_t ws_size,
                              hipStream_t stream) {
  (void)in_sizes; (void)n_in; (void)out_size; (void)ws_size;
  const float* x    = (const float*)d_in[0];
  const float* pw   = (const float*)d_in[1];
  const float* pb   = (const float*)d_in[2];
  const float* cls  = (const float*)d_in[3];
  const float* pos  = (const float*)d_in[4];
  const float* ln_g = (const float*)d_in[5];
  const float* ln_b = (const float*)d_in[6];
  const float* wx   = (const float*)d_in[7];
  const float* bx   = (const float*)d_in[8];
  const float* wz   = (const float*)d_in[9];
  const float* bz   = (const float*)d_in[10];
  const float* kwf  = (const float*)d_in[11];
  const float* kbf  = (const float*)d_in[12];
  const float* kwb  = (const float*)d_in[13];
  const float* kbb  = (const float*)d_in[14];
  const float* bfw  = (const float*)d_in[15];
  const float* bfb  = (const float*)d_in[16];
  const float* cfw  = (const float*)d_in[17];
  const float* cfb  = (const float*)d_in[18];
  const float* dfw  = (const float*)d_in[19];
  const float* dfb  = (const float*)d_in[20];
  const float* dtf  = (const float*)d_in[21];
  const float* af   = (const float*)d_in[22];
  const float* bbw  = (const float*)d_in[23];
  const float* bbb  = (const float*)d_in[24];
  const float* cbw  = (const float*)d_in[25];
  const float* cbb  = (const float*)d_in[26];
  const float* dbw  = (const float*)d_in[27];
  const float* dbb  = (const float*)d_in[28];
  const float* dtb  = (const float*)d_in[29];
  const float* ab   = (const float*)d_in[30];
  const float* wo   = (const float*)d_in[31];
  const float* bo   = (const float*)d_in[32];
  const float* fg   = (const float*)d_in[33];
  const float* fb   = (const float*)d_in[34];

  char* wsb = (char*)d_ws;
  size_t off = 0;
  auto carve = [&](size_t bytes) -> char* {
    char* p = wsb + off;
    off += (bytes + 255) & ~(size_t)255;
    return p;
  };
  float* t_buf = (float*)carve((size_t)NROWS*DIM*4);
  float* xpz   = (float*)carve((size_t)NROWS*2*EDIM*4);
  float* xf    = (float*)carve((size_t)PADROWS*EDIM*4);   // reused as im2col (1600x768)
  float* xb    = (float*)carve((size_t)PADROWS*EDIM*4);
  float* yacc  = (float*)carve((size_t)NROWS*EDIM*4);
  u16*   Abf   = (u16*)carve((size_t)PADROWS*EDIM*2);     // LN-out (K=384) / gate-out (K=768)
  u16*   Af    = (u16*)carve((size_t)PADROWS*EDIM*2);
  u16*   Ab    = (u16*)carve((size_t)PADROWS*EDIM*2);
  u16*   Wbf   = (u16*)carve((size_t)NBIG*EDIM*2);
  float* biasb = (float*)carve((size_t)NBIG*4);
  float* hend  = (float*)carve((size_t)NCH*SCANT*4);
  float* pend  = (float*)carve((size_t)NCH*SCANT*4);
  float* Hcar  = (float*)carve((size_t)NCH*SCANT*4);
  u16*   BC    = (u16*)carve((size_t)NROWS*NBIG*2);

  // ---- patch embed (fp32 path) ----
  im2col_k<<<CDIV(1600*768,256),256,0,stream>>>(xf, x);
  patch_gemm_k<<<25*6,256,0,stream>>>(xf, pw, pb, pos, t_buf);
  cls_add_k<<<CDIV(NBATCH*DIM,256),256,0,stream>>>(t_buf, cls, pos);

  const int PREP0 = CDIV(2*EDIM*DIM + 2*EDIM + 3, 4);          // threads
  const int PREP1 = CDIV(2*ENC*EDIM + EDIM*EDIM + NBIG + 3, 4);
  const int PREPO = CDIV(DIM*EDIM + 3, 4);

  for (int i = 0; i < 2; ++i) {
    const float* lng  = ln_g + i*DIM;            const float* lnb  = ln_b + i*DIM;
    const float* wxi  = wx + (size_t)i*EDIM*DIM; const float* bxi  = bx + i*EDIM;
    const float* wzi  = wz + (size_t)i*EDIM*DIM; const float* bzi  = bz + i*EDIM;
    const float* kwfi = kwf + i*EDIM*3;          const float* kbfi = kbf + i*EDIM;
    const float* kwbi = kwb + i*EDIM*3;          const float* kbbi = kbb + i*EDIM;
    const float* bfwi = bfw + (size_t)i*ENC*EDIM;  const float* bfbi = bfb + i*ENC;
    const float* cfwi = cfw + (size_t)i*ENC*EDIM;  const float* cfbi = cfb + i*ENC;
    const float* dfwi = dfw + (size_t)i*EDIM*EDIM; const float* dfbi = dfb + i*EDIM;
    const float* dtfi = dtf + i*EDIM;              const float* afi  = af + i*EDIM*NST;
    const float* bbwi = bbw + (size_t)i*ENC*EDIM;  const float* bbbi = bbb + i*ENC;
    const float* cbwi = cbw + (size_t)i*ENC*EDIM;  const float* cbbi = cbb + i*ENC;
    const float* dbwi = dbw + (size_t)i*EDIM*EDIM; const float* dbbi = dbb + i*EDIM;
    const float* dtbi = dtb + i*EDIM;              const float* abi  = ab + i*EDIM*NST;
    const float* woi  = wo + (size_t)i*DIM*EDIM;   const float* boi  = bo + i*DIM;

    ln_bf_k<<<PADROWS,64,0,stream>>>(t_buf, lng, lnb, Abf);
    prep_k<<<CDIV(PREP0,256),256,0,stream>>>(Wbf, wxi, EDIM*DIM, wzi, EDIM*DIM, nullptr, 0,
                                             biasb, bxi, EDIM, bzi, EDIM, nullptr, nullptr, 0);
    gemm_k<0><<<13*12,256,0,stream>>>(Abf, Wbf, biasb, xpz, NROWS, 2*EDIM, DIM, 13);

    dwconv2_k<<<CDIV(PADROWS*EDIM,256),256,0,stream>>>(xpz, kwfi, kbfi, kwbi, kbbi, xf, xb, Af, Ab, Abf);

    // ---- forward branch: fused [B;C;delta] projection + chunked scan ----
    prep_k<<<CDIV(PREP1,256),256,0,stream>>>(Wbf, bfwi, ENC*EDIM, cfwi, ENC*EDIM, dfwi, EDIM*EDIM,
                                             biasb, bfbi, ENC, cfbi, ENC, dfbi, dtfi, EDIM);
    gemm_k<1><<<13*198,256,0,stream>>>(Af, Wbf, biasb, BC, NROWS, NBIG, EDIM, 13);
    scan_part_k<<<dim3(12,NBATCH,NCH),256,0,stream>>>(BC, xf, afi, hend, pend, 0);
    scan_carry_k<<<CDIV(SCANT,256),256,0,stream>>>(hend, pend, Hcar);
    scan_emit_k<<<dim3(12,NBATCH,NCH),256,0,stream>>>(BC, xf, afi, Hcar, yacc, nullptr, nullptr, 0, 0);

    // ---- backward branch (emit fuses the gate; writes bf16 Abf directly) ----
    prep_k<<<CDIV(PREP1,256),256,0,stream>>>(Wbf, bbwi, ENC*EDIM, cbwi, ENC*EDIM, dbwi, EDIM*EDIM,
                                             biasb, bbbi, ENC, cbbi, ENC, dbbi, dtbi, EDIM);
    gemm_k<1><<<13*198,256,0,stream>>>(Ab, Wbf, biasb, BC, NROWS, NBIG, EDIM, 13);
    scan_part_k<<<dim3(12,NBATCH,NCH),256,0,stream>>>(BC, xb, abi, hend, pend, 1);
    scan_carry_k<<<CDIV(SCANT,256),256,0,stream>>>(hend, pend, Hcar);
    scan_emit_k<<<dim3(12,NBATCH,NCH),256,0,stream>>>(BC, xb, abi, Hcar, yacc, xpz, Abf, 1, 1);

    // ---- output projection (residual accumulate, fp32 t) ----
    prep_k<<<CDIV(PREPO,256),256,0,stream>>>(Wbf, woi, DIM*EDIM, nullptr, 0, nullptr, 0,
                                             nullptr, nullptr, 0, nullptr, 0, nullptr, nullptr, 0);
    gemm_k<2><<<13*3,256,0,stream>>>(Abf, Wbf, boi, t_buf, NROWS, DIM, EDIM, 13);
  }

  ln_k<<<NROWS,64,0,stream>>>(t_buf, fg, fb, (float*)d_out);
}

// Round 12
// 1119.236 us; speedup vs baseline: 1.3360x; 1.3360x over previous
//
#include <hip/hip_runtime.h>

#define CDIV(a,b) (((a)+(b)-1)/(b))

typedef unsigned short u16;
typedef __attribute__((ext_vector_type(8))) short s16x8;
typedef __attribute__((ext_vector_type(4))) float fx4;

#define NBATCH 8
#define MTOK 197
#define DIM 384
#define EDIM 768
#define NST 16
#define NROWS (NBATCH*MTOK)      // 1576
#define PADROWS 1664             // 13*128
#define ENC (EDIM*NST)           // 12288
#define NBIG (2*ENC+EDIM)        // 25344
#define NCH 16                   // scan chunks
#define CLEN 13                  // ceil(197/16)
#define SCANT (NBATCH*EDIM*NST)  // 98304 scan lanes

__device__ __forceinline__ u16 f2b(float f) {
  union { float f; unsigned u; } v; v.f = f;
  unsigned r = v.u + 0x7fffu + ((v.u >> 16) & 1u);
  return (u16)(r >> 16);
}
__device__ __forceinline__ float b2f(u16 u) {
  union { unsigned u; float f; } v; v.u = ((unsigned)u) << 16;
  return v.f;
}
__device__ __forceinline__ float silu_f(float x) { return x / (1.f + __expf(-x)); }
__device__ __forceinline__ float softplus_f(float x) {
  return (x > 15.f) ? x : log1pf(__expf(x));
}

#define GLD16(g, l) __builtin_amdgcn_global_load_lds( \
    (const __attribute__((address_space(1))) void*)(g), \
    (__attribute__((address_space(3))) void*)(l), 16, 0, 0)

// bijective XCD-contiguous block remap [m204]
__device__ __forceinline__ int xcd_swz(int orig, int nwg) {
  int q = nwg >> 3, r = nwg & 7;
  int xcd = orig & 7, pos = orig >> 3;
  return (xcd < r ? xcd*(q+1) : r*(q+1) + (xcd-r)*q) + pos;
}

// ---------------------------------------------------------------- im2col
__global__ void im2col_k(float* __restrict__ dst, const float* __restrict__ x) {
  int i = blockIdx.x*blockDim.x + threadIdx.x;
  if (i >= 1600*768) return;
  int col = i % 768, r = i / 768;
  float v = 0.f;
  if (r < 1568) {
    int b = r / 196, p = r % 196;
    int py = p / 14, px = p % 14;
    int c = col >> 8, rem = col & 255;
    int ph = rem >> 4, pw_ = rem & 15;
    v = x[((b*3 + c)*224 + py*16 + ph)*224 + px*16 + pw_];
  }
  dst[i] = v;
}

// --------------------------------------------- fp32 patch-embed GEMM (precision-critical)
__global__ __launch_bounds__(256) void patch_gemm_k(
    const float* __restrict__ A, const float* __restrict__ W,
    const float* __restrict__ pb, const float* __restrict__ pos, float* __restrict__ t) {
  __shared__ float As[64][17], Ws[64][17];
  int bx = blockIdx.x % 25, by = blockIdx.x / 25;
  int tid = threadIdx.x;
  int tx = tid & 15, ty = tid >> 4;
  float acc[4][4] = {};
  for (int kk = 0; kk < 768; kk += 16) {
    #pragma unroll
    for (int l = 0; l < 4; ++l) {
      int e = tid + l*256;
      int r = e >> 4, c = e & 15;
      As[r][c] = A[(size_t)(bx*64 + r)*768 + kk + c];
      Ws[r][c] = W[(size_t)(by*64 + r)*768 + kk + c];
    }
    __syncthreads();
    #pragma unroll
    for (int k = 0; k < 16; ++k) {
      float av[4], bv[4];
      #pragma unroll
      for (int i2 = 0; i2 < 4; ++i2) av[i2] = As[ty*4+i2][k];
      #pragma unroll
      for (int j = 0; j < 4; ++j) bv[j] = Ws[tx*4+j][k];
      #pragma unroll
      for (int i2 = 0; i2 < 4; ++i2)
        #pragma unroll
        for (int j = 0; j < 4; ++j)
          acc[i2][j] += av[i2]*bv[j];
    }
    __syncthreads();
  }
  #pragma unroll
  for (int i2 = 0; i2 < 4; ++i2) {
    int R = bx*64 + ty*4 + i2;
    if (R >= 1568) continue;
    int b = R / 196, p = R % 196;
    float* trow = t + ((size_t)b*MTOK + 1 + p)*DIM;
    const float* prow = pos + (size_t)(1+p)*DIM;
    #pragma unroll
    for (int j = 0; j < 4; ++j) {
      int Dd = by*64 + tx*4 + j;
      trow[Dd] = acc[i2][j] + pb[Dd] + prow[Dd];
    }
  }
}

__global__ void cls_add_k(float* __restrict__ t, const float* __restrict__ cls,
                          const float* __restrict__ pos) {
  int i = blockIdx.x*blockDim.x + threadIdx.x;
  if (i >= NBATCH*DIM) return;
  int b = i / DIM, d = i % DIM;
  t[(size_t)b*MTOK*DIM + d] = cls[d] + pos[d];
}

// ---------------------------------------------------------------- final LayerNorm (f32 out)
__global__ __launch_bounds__(64) void ln_k(const float* __restrict__ x,
    const float* __restrict__ g, const float* __restrict__ bb, float* __restrict__ y) {
  int row = blockIdx.x, lane = threadIdx.x;
  const float* xr = x + (size_t)row*DIM;
  float v[6]; float s = 0.f;
  #pragma unroll
  for (int i = 0; i < 6; ++i) { v[i] = xr[lane + i*64]; s += v[i]; }
  #pragma unroll
  for (int o = 32; o >= 1; o >>= 1) s += __shfl_xor(s, o);
  float mean = s * (1.f/DIM);
  float q = 0.f;
  #pragma unroll
  for (int i = 0; i < 6; ++i) { float d = v[i]-mean; q += d*d; }
  #pragma unroll
  for (int o = 32; o >= 1; o >>= 1) q += __shfl_xor(q, o);
  float rstd = rsqrtf(q*(1.f/DIM) + 1e-5f);
  float* yr = y + (size_t)row*DIM;
  #pragma unroll
  for (int i = 0; i < 6; ++i) {
    int c = lane + i*64;
    yr[c] = (v[i]-mean)*rstd*g[c] + bb[c];
  }
}

// ---------------------------- per-layer LayerNorm -> bf16 padded A (rows>=NROWS zeroed)
__global__ __launch_bounds__(64) void ln_bf_k(const float* __restrict__ x,
    const float* __restrict__ g, const float* __restrict__ bb, u16* __restrict__ y) {
  int row = blockIdx.x, lane = threadIdx.x;
  u16* yr = y + (size_t)row*DIM;
  if (row >= NROWS) {
    #pragma unroll
    for (int i = 0; i < 6; ++i) yr[lane + i*64] = 0;
    return;
  }
  const float* xr = x + (size_t)row*DIM;
  float v[6]; float s = 0.f;
  #pragma unroll
  for (int i = 0; i < 6; ++i) { v[i] = xr[lane + i*64]; s += v[i]; }
  #pragma unroll
  for (int o = 32; o >= 1; o >>= 1) s += __shfl_xor(s, o);
  float mean = s * (1.f/DIM);
  float q = 0.f;
  #pragma unroll
  for (int i = 0; i < 6; ++i) { float d = v[i]-mean; q += d*d; }
  #pragma unroll
  for (int o = 32; o >= 1; o >>= 1) q += __shfl_xor(q, o);
  float rstd = rsqrtf(q*(1.f/DIM) + 1e-5f);
  #pragma unroll
  for (int i = 0; i < 6; ++i) {
    int c = lane + i*64;
    yr[c] = f2b((v[i]-mean)*rstd*g[c] + bb[c]);
  }
}

// --------------- fused prep: up to-3-segment weight fp32->bf16 + bias concat (f32)
__global__ void prep_k(u16* __restrict__ wdst,
                       const float* __restrict__ w1, int n1,
                       const float* __restrict__ w2, int n2,
                       const float* __restrict__ w3, int n3,
                       float* __restrict__ bdst,
                       const float* __restrict__ b1, int m1,
                       const float* __restrict__ b2, int m2,
                       const float* __restrict__ b3a, const float* __restrict__ b3b, int m3) {
  int ntw = n1 + n2 + n3;
  int i4 = (blockIdx.x*blockDim.x + threadIdx.x)*4;
  if (i4 < ntw) {
    const float* src; int off;
    if (i4 < n1)           { src = w1; off = i4; }
    else if (i4 < n1+n2)   { src = w2; off = i4-n1; }
    else                   { src = w3; off = i4-n1-n2; }
    float4 v = *(const float4*)(src + off);
    *(ushort4*)(wdst + i4) = make_ushort4(f2b(v.x), f2b(v.y), f2b(v.z), f2b(v.w));
  } else {
    int j = i4 - ntw;
    int mt = m1 + m2 + m3;
    #pragma unroll
    for (int k2 = 0; k2 < 4; ++k2) {
      int j2 = j + k2;
      if (j2 < mt) {
        float v;
        if (j2 < m1)          v = b1[j2];
        else if (j2 < m1+m2)  v = b2[j2-m1];
        else { int t2 = j2-m1-m2; v = b3a[t2] + b3b[t2]; }
        bdst[j2] = v;
      }
    }
  }
}

// ---------------------------------------------------------------- bf16 MFMA GEMM (m97 structure + XCD swizzle)
// A: [rows_padded][K] bf16 row-major, W: [N][K] bf16 row-major (i.e. B^T), out = A*W^T + bias
// MODE 0: f32 out; MODE 1: bf16 out; MODE 2: f32 out += (residual accumulate)
// NOTE: (256,4) is measured-good (R7: 108.5us, WRITE=81MB). (256,5) caused 5x write
// amplification on the u16 epilogue (R10: 190us, WRITE=406MB) — L2 partial-line thrash.
template<int MODE>
__global__ __launch_bounds__(256, 4) void gemm_k(
    const u16* __restrict__ A, const u16* __restrict__ W,
    const float* __restrict__ bias, void* __restrict__ outp,
    int Mvalid, int N, int K, int nRT) {
  __shared__ u16 As[128*64];
  __shared__ u16 Bs[128*64];
  int bid = xcd_swz(blockIdx.x, gridDim.x);
  int rt = bid % nRT, ct = bid / nRT;   // col-major grid: consecutive logical blocks share W panel
  int tid = threadIdx.x;
  int w = tid >> 6, lane = tid & 63;
  int wm = w >> 1, wn = w & 1;
  fx4 acc[4][4];
  #pragma unroll
  for (int i = 0; i < 4; ++i)
    #pragma unroll
    for (int j = 0; j < 4; ++j) acc[i][j] = (fx4)0.f;

  int lrow = lane >> 3;
  int lcol = (lane & 7) * 8;
  size_t abase = (size_t)(rt*128) * K + lcol;
  size_t wbase = (size_t)(ct*128) * K + lcol;

  for (int kk = 0; kk < K; kk += 64) {
    #pragma unroll
    for (int c = 0; c < 4; ++c) {
      int chunk = c*4 + w;
      int row = chunk*8 + lrow;
      GLD16(A + abase + (size_t)row*K + kk, As + chunk*512);
      GLD16(W + wbase + (size_t)row*K + kk, Bs + chunk*512);
    }
    __syncthreads();
    #pragma unroll
    for (int ks = 0; ks < 2; ++ks) {
      s16x8 afr[4], bfr[4];
      #pragma unroll
      for (int f = 0; f < 4; ++f) {
        int ar = wm*64 + f*16 + (lane & 15);
        afr[f] = *(const s16x8*)(As + ar*64 + ks*32 + (lane>>4)*8);
        int br = wn*64 + f*16 + (lane & 15);
        bfr[f] = *(const s16x8*)(Bs + br*64 + ks*32 + (lane>>4)*8);
      }
      #pragma unroll
      for (int i = 0; i < 4; ++i)
        #pragma unroll
        for (int j = 0; j < 4; ++j)
          acc[i][j] = __builtin_amdgcn_mfma_f32_16x16x32_bf16(afr[i], bfr[j], acc[i][j], 0, 0, 0);
    }
    __syncthreads();
  }
  // epilogue: C/D layout col=lane&15, row=4*(lane>>4)+reg  [verified m89/m91]
  #pragma unroll
  for (int i = 0; i < 4; ++i) {
    int rbase = rt*128 + wm*64 + i*16 + (lane>>4)*4;
    #pragma unroll
    for (int j = 0; j < 4; ++j) {
      int Cc = ct*128 + wn*64 + j*16 + (lane & 15);
      float bv = bias[Cc];
      #pragma unroll
      for (int r = 0; r < 4; ++r) {
        int R = rbase + r;
        if (R < Mvalid) {
          float v = acc[i][j][r] + bv;
          if (MODE == 0)      ((float*)outp)[(size_t)R*N + Cc] = v;
          else if (MODE == 1) ((u16*)outp)[(size_t)R*N + Cc] = f2b(v);
          else { float* o = (float*)outp + (size_t)R*N + Cc; *o += v; }
        }
      }
    }
  }
}

// -------- fused fwd+bwd depthwise conv (token dim) + silu -> f32 X and bf16 padded A
// also zeroes the pad rows of the 768-wide gate output buffer (gabf)
__global__ void dwconv2_k(const float* __restrict__ xpz,
                          const float* __restrict__ kwf, const float* __restrict__ kbf,
                          const float* __restrict__ kwb, const float* __restrict__ kbb,
                          float* __restrict__ outf, float* __restrict__ outb,
                          u16* __restrict__ af16, u16* __restrict__ ab16,
                          u16* __restrict__ gabf) {
  int i = blockIdx.x*blockDim.x + threadIdx.x;
  if (i >= PADROWS*EDIM) return;
  int e = i % EDIM, r = i / EDIM;
  if (r >= NROWS) { af16[i] = 0; ab16[i] = 0; gabf[i] = 0; return; }
  int t = r % MTOK;
  const float* base = xpz + (size_t)r*(2*EDIM) + e;  // xp at col offset 0, ld=1536
  float xm = (t > 0)        ? base[-(2*EDIM)] : 0.f;
  float x0 = base[0];
  float xp = (t < MTOK-1)   ? base[ (2*EDIM)] : 0.f;
  float vf = silu_f(kbf[e] + xm*kwf[e*3+0] + x0*kwf[e*3+1] + xp*kwf[e*3+2]);
  float vb = silu_f(kbb[e] + xm*kwb[e*3+0] + x0*kwb[e*3+1] + xp*kwb[e*3+2]);
  outf[i] = vf; outb[i] = vb;
  af16[i] = f2b(vf); ab16[i] = f2b(vb);
}

// ---------------------------------------------------------------- chunked selective scan (vectorized)
// 4 n-states per lane: B/C load as ushort4 (8B), h/P/H0 as float4. 16 e per wave group of 4 lanes.
// BC row layout: [0,12288)=B, [12288,24576)=C, [24576,25344)=delta_pre.
__global__ __launch_bounds__(256) void scan_part_k(const u16* __restrict__ BC,
    const float* __restrict__ X, const float* __restrict__ afp,
    float* __restrict__ hend, float* __restrict__ pend, int rev) {
  int w = threadIdx.x >> 6, lane = threadIdx.x & 63;
  int b = blockIdx.y, c = blockIdx.z;
  int e = blockIdx.x*64 + w*16 + (lane >> 2);
  int n0 = (lane & 3) * 4;
  float4 ac = *(const float4*)(afp + e*NST + n0);
  size_t rb = (size_t)b*MTOK;
  int tau0 = c*CLEN;
  int tauE = min(MTOK-1, tau0 + CLEN - 1);
  float h0=0.f,h1=0.f,h2=0.f,h3=0.f, P0=1.f,P1=1.f,P2=1.f,P3=1.f;
  int t0 = rev ? (MTOK-1-tau0) : tau0;
  const u16* q0 = BC + (rb + t0)*NBIG;
  ushort4 Bv = *(const ushort4*)(q0 + e*NST + n0);
  u16 dpu = q0[2*ENC + e];
  float Xv = X[(rb + t0)*EDIM + e];
  for (int tau = tau0; tau <= tauE; ++tau) {
    ushort4 nB = make_ushort4(0,0,0,0); u16 ndp = 0; float nX = 0.f;
    if (tau + 1 <= tauE) {
      int tn = rev ? (MTOK-2-tau) : (tau+1);
      const u16* qn = BC + (rb + tn)*NBIG;
      nB = *(const ushort4*)(qn + e*NST + n0);
      ndp = qn[2*ENC + e];
      nX = X[(rb + tn)*EDIM + e];
    }
    float delta = softplus_f(b2f(dpu));
    float dx = delta * Xv;
    float a0 = delta*ac.x, a1 = delta*ac.y, a2 = delta*ac.z, a3 = delta*ac.w;
    h0 = a0*h0 + b2f(Bv.x)*dx;  P0 *= a0;
    h1 = a1*h1 + b2f(Bv.y)*dx;  P1 *= a1;
    h2 = a2*h2 + b2f(Bv.z)*dx;  P2 *= a2;
    h3 = a3*h3 + b2f(Bv.w)*dx;  P3 *= a3;
    Bv = nB; dpu = ndp; Xv = nX;
  }
  size_t ci = (size_t)c*SCANT + ((size_t)b*EDIM + e)*NST + n0;
  *(float4*)(hend + ci) = make_float4(h0,h1,h2,h3);
  *(float4*)(pend + ci) = make_float4(P0,P1,P2,P3);
}

// Phase 2: sequential carry combine across chunks (tiny)
__global__ void scan_carry_k(const float* __restrict__ hend, const float* __restrict__ pend,
                             float* __restrict__ H0) {
  int i = blockIdx.x*blockDim.x + threadIdx.x;
  if (i >= SCANT) return;
  float H = 0.f;
  #pragma unroll
  for (int c = 0; c < NCH; ++c) {
    size_t ci = (size_t)c*SCANT + i;
    H0[ci] = H;
    H = pend[ci]*H + hend[ci];
  }
}

// Phase 3: re-run chunk recurrence from exact carry-in, emit y = sum_n h*C.
// gate=0: Y[t,e] = ps (forward). gate=1: final=(Y[t,e]+ps); gdst[t,e]=bf16(final*silu(z)).
__global__ __launch_bounds__(256) void scan_emit_k(const u16* __restrict__ BC,
    const float* __restrict__ X, const float* __restrict__ afp,
    const float* __restrict__ H0, float* __restrict__ Y,
    const float* __restrict__ xpz, u16* __restrict__ gdst, int rev, int gate) {
  int w = threadIdx.x >> 6, lane = threadIdx.x & 63;
  int b = blockIdx.y, c = blockIdx.z;
  int e = blockIdx.x*64 + w*16 + (lane >> 2);
  int n0 = (lane & 3) * 4;
  float4 ac = *(const float4*)(afp + e*NST + n0);
  size_t rb = (size_t)b*MTOK;
  int tau0 = c*CLEN;
  int tauE = min(MTOK-1, tau0 + CLEN - 1);
  float4 hh = *(const float4*)(H0 + (size_t)c*SCANT + ((size_t)b*EDIM + e)*NST + n0);
  float h0 = hh.x, h1 = hh.y, h2 = hh.z, h3 = hh.w;
  int t0 = rev ? (MTOK-1-tau0) : tau0;
  const u16* q0 = BC + (rb + t0)*NBIG;
  ushort4 Bv = *(const ushort4*)(q0 + e*NST + n0);
  ushort4 Cv = *(const ushort4*)(q0 + ENC + e*NST + n0);
  u16 dpu = q0[2*ENC + e];
  float Xv = X[(rb + t0)*EDIM + e];
  for (int tau = tau0; tau <= tauE; ++tau) {
    int t = rev ? (MTOK-1-tau) : tau;
    ushort4 nB = make_ushort4(0,0,0,0), nC = make_ushort4(0,0,0,0);
    u16 ndp = 0; float nX = 0.f;
    if (tau + 1 <= tauE) {
      int tn = rev ? (MTOK-2-tau) : (tau+1);
      const u16* qn = BC + (rb + tn)*NBIG;
      nB = *(const ushort4*)(qn + e*NST + n0);
      nC = *(const ushort4*)(qn + ENC + e*NST + n0);
      ndp = qn[2*ENC + e];
      nX = X[(rb + tn)*EDIM + e];
    }
    float delta = softplus_f(b2f(dpu));
    float dx = delta * Xv;
    h0 = (delta*ac.x)*h0 + b2f(Bv.x)*dx;
    h1 = (delta*ac.y)*h1 + b2f(Bv.y)*dx;
    h2 = (delta*ac.z)*h2 + b2f(Bv.z)*dx;
    h3 = (delta*ac.w)*h3 + b2f(Bv.w)*dx;
    float ps = h0*b2f(Cv.x) + h1*b2f(Cv.y) + h2*b2f(Cv.z) + h3*b2f(Cv.w);
    ps += __shfl_xor(ps, 1); ps += __shfl_xor(ps, 2);
    if ((lane & 3) == 0) {
      size_t idx = (rb + t)*EDIM + e;
      if (gate) {
        float yv = Y[idx] + ps;
        float z = xpz[(rb + t)*(size_t)(2*EDIM) + EDIM + e];
        gdst[idx] = f2b(yv * silu_f(z));
      } else {
        Y[idx] = ps;
      }
    }
    Bv = nB; Cv = nC; dpu = ndp; Xv = nX;
  }
}

// ================================================================ host
extern "C" void kernel_launch(void* const* d_in, const int* in_sizes, int n_in,
                              void* d_out, int out_size, void* d_ws, size_t ws_size,
                              hipStream_t stream) {
  (void)in_sizes; (void)n_in; (void)out_size; (void)ws_size;
  const float* x    = (const float*)d_in[0];
  const float* pw   = (const float*)d_in[1];
  const float* pb   = (const float*)d_in[2];
  const float* cls  = (const float*)d_in[3];
  const float* pos  = (const float*)d_in[4];
  const float* ln_g = (const float*)d_in[5];
  const float* ln_b = (const float*)d_in[6];
  const float* wx   = (const float*)d_in[7];
  const float* bx   = (const float*)d_in[8];
  const float* wz   = (const float*)d_in[9];
  const float* bz   = (const float*)d_in[10];
  const float* kwf  = (const float*)d_in[11];
  const float* kbf  = (const float*)d_in[12];
  const float* kwb  = (const float*)d_in[13];
  const float* kbb  = (const float*)d_in[14];
  const float* bfw  = (const float*)d_in[15];
  const float* bfb  = (const float*)d_in[16];
  const float* cfw  = (const float*)d_in[17];
  const float* cfb  = (const float*)d_in[18];
  const float* dfw  = (const float*)d_in[19];
  const float* dfb  = (const float*)d_in[20];
  const float* dtf  = (const float*)d_in[21];
  const float* af   = (const float*)d_in[22];
  const float* bbw  = (const float*)d_in[23];
  const float* bbb  = (const float*)d_in[24];
  const float* cbw  = (const float*)d_in[25];
  const float* cbb  = (const float*)d_in[26];
  const float* dbw  = (const float*)d_in[27];
  const float* dbb  = (const float*)d_in[28];
  const float* dtb  = (const float*)d_in[29];
  const float* ab   = (const float*)d_in[30];
  const float* wo   = (const float*)d_in[31];
  const float* bo   = (const float*)d_in[32];
  const float* fg   = (const float*)d_in[33];
  const float* fb   = (const float*)d_in[34];

  char* wsb = (char*)d_ws;
  size_t off = 0;
  auto carve = [&](size_t bytes) -> char* {
    char* p = wsb + off;
    off += (bytes + 255) & ~(size_t)255;
    return p;
  };
  float* t_buf = (float*)carve((size_t)NROWS*DIM*4);
  float* xpz   = (float*)carve((size_t)NROWS*2*EDIM*4);
  float* xf    = (float*)carve((size_t)PADROWS*EDIM*4);   // reused as im2col (1600x768)
  float* xb    = (float*)carve((size_t)PADROWS*EDIM*4);
  float* yacc  = (float*)carve((size_t)NROWS*EDIM*4);
  u16*   Abf   = (u16*)carve((size_t)PADROWS*EDIM*2);     // LN-out (K=384) / gate-out (K=768)
  u16*   Af    = (u16*)carve((size_t)PADROWS*EDIM*2);
  u16*   Ab    = (u16*)carve((size_t)PADROWS*EDIM*2);
  u16*   Wbf   = (u16*)carve((size_t)NBIG*EDIM*2);
  float* biasb = (float*)carve((size_t)NBIG*4);
  float* hend  = (float*)carve((size_t)NCH*SCANT*4);
  float* pend  = (float*)carve((size_t)NCH*SCANT*4);
  float* Hcar  = (float*)carve((size_t)NCH*SCANT*4);
  u16*   BC    = (u16*)carve((size_t)NROWS*NBIG*2);

  // ---- patch embed (fp32 path) ----
  im2col_k<<<CDIV(1600*768,256),256,0,stream>>>(xf, x);
  patch_gemm_k<<<25*6,256,0,stream>>>(xf, pw, pb, pos, t_buf);
  cls_add_k<<<CDIV(NBATCH*DIM,256),256,0,stream>>>(t_buf, cls, pos);

  const int PREP0 = CDIV(2*EDIM*DIM + 2*EDIM + 3, 4);          // threads
  const int PREP1 = CDIV(2*ENC*EDIM + EDIM*EDIM + NBIG + 3, 4);
  const int PREPO = CDIV(DIM*EDIM + 3, 4);

  for (int i = 0; i < 2; ++i) {
    const float* lng  = ln_g + i*DIM;            const float* lnb  = ln_b + i*DIM;
    const float* wxi  = wx + (size_t)i*EDIM*DIM; const float* bxi  = bx + i*EDIM;
    const float* wzi  = wz + (size_t)i*EDIM*DIM; const float* bzi  = bz + i*EDIM;
    const float* kwfi = kwf + i*EDIM*3;          const float* kbfi = kbf + i*EDIM;
    const float* kwbi = kwb + i*EDIM*3;          const float* kbbi = kbb + i*EDIM;
    const float* bfwi = bfw + (size_t)i*ENC*EDIM;  const float* bfbi = bfb + i*ENC;
    const float* cfwi = cfw + (size_t)i*ENC*EDIM;  const float* cfbi = cfb + i*ENC;
    const float* dfwi = dfw + (size_t)i*EDIM*EDIM; const float* dfbi = dfb + i*EDIM;
    const float* dtfi = dtf + i*EDIM;              const float* afi  = af + i*EDIM*NST;
    const float* bbwi = bbw + (size_t)i*ENC*EDIM;  const float* bbbi = bbb + i*ENC;
    const float* cbwi = cbw + (size_t)i*ENC*EDIM;  const float* cbbi = cbb + i*ENC;
    const float* dbwi = dbw + (size_t)i*EDIM*EDIM; const float* dbbi = dbb + i*EDIM;
    const float* dtbi = dtb + i*EDIM;              const float* abi  = ab + i*EDIM*NST;
    const float* woi  = wo + (size_t)i*DIM*EDIM;   const float* boi  = bo + i*DIM;

    ln_bf_k<<<PADROWS,64,0,stream>>>(t_buf, lng, lnb, Abf);
    prep_k<<<CDIV(PREP0,256),256,0,stream>>>(Wbf, wxi, EDIM*DIM, wzi, EDIM*DIM, nullptr, 0,
                                             biasb, bxi, EDIM, bzi, EDIM, nullptr, nullptr, 0);
    gemm_k<0><<<13*12,256,0,stream>>>(Abf, Wbf, biasb, xpz, NROWS, 2*EDIM, DIM, 13);

    dwconv2_k<<<CDIV(PADROWS*EDIM,256),256,0,stream>>>(xpz, kwfi, kbfi, kwbi, kbbi, xf, xb, Af, Ab, Abf);

    // ---- forward branch: fused [B;C;delta] projection + chunked scan ----
    prep_k<<<CDIV(PREP1,256),256,0,stream>>>(Wbf, bfwi, ENC*EDIM, cfwi, ENC*EDIM, dfwi, EDIM*EDIM,
                                             biasb, bfbi, ENC, cfbi, ENC, dfbi, dtfi, EDIM);
    gemm_k<1><<<13*198,256,0,stream>>>(Af, Wbf, biasb, BC, NROWS, NBIG, EDIM, 13);
    scan_part_k<<<dim3(12,NBATCH,NCH),256,0,stream>>>(BC, xf, afi, hend, pend, 0);
    scan_carry_k<<<CDIV(SCANT,256),256,0,stream>>>(hend, pend, Hcar);
    scan_emit_k<<<dim3(12,NBATCH,NCH),256,0,stream>>>(BC, xf, afi, Hcar, yacc, nullptr, nullptr, 0, 0);

    // ---- backward branch (emit fuses the gate; writes bf16 Abf directly) ----
    prep_k<<<CDIV(PREP1,256),256,0,stream>>>(Wbf, bbwi, ENC*EDIM, cbwi, ENC*EDIM, dbwi, EDIM*EDIM,
                                             biasb, bbbi, ENC, cbbi, ENC, dbbi, dtbi, EDIM);
    gemm_k<1><<<13*198,256,0,stream>>>(Ab, Wbf, biasb, BC, NROWS, NBIG, EDIM, 13);
    scan_part_k<<<dim3(12,NBATCH,NCH),256,0,stream>>>(BC, xb, abi, hend, pend, 1);
    scan_carry_k<<<CDIV(SCANT,256),256,0,stream>>>(hend, pend, Hcar);
    scan_emit_k<<<dim3(12,NBATCH,NCH),256,0,stream>>>(BC, xb, abi, Hcar, yacc, xpz, Abf, 1, 1);

    // ---- output projection (residual accumulate, fp32 t) ----
    prep_k<<<CDIV(PREPO,256),256,0,stream>>>(Wbf, woi, DIM*EDIM, nullptr, 0, nullptr, 0,
                                             nullptr, nullptr, 0, nullptr, 0, nullptr, nullptr, 0);
    gemm_k<2><<<13*3,256,0,stream>>>(Abf, Wbf, boi, t_buf, NROWS, DIM, EDIM, 13);
  }

  ln_k<<<NROWS,64,0,stream>>>(t_buf, fg, fb, (float*)d_out);
}